// Round 4
// baseline (471.385 us; speedup 1.0000x reference)
//
#include <hip/hip_runtime.h>

// Problem sizes (fixed by the reference)
#define BDIM 8
#define QDIM 1024
#define KDIM 1024
#define HDIM 64   // = DQ = DK = DV

constexpr float kLog2e = 1.4426950408889634f;
constexpr float kC2 = 2.0f * kLog2e;

// tanh(x) = 1 - 2/(1 + e^{2x}), e^{2x} = 2^{kC2*x} = Eq*Ek with
// Eq = 2^{kC2*qhat}, Ek = 2^{kC2*khat} precomputed in the projections.
// Per-element: sig = rcp(fma(Eq,Ek,1)); score = sumw - 2*sum w*sig.
__device__ __forceinline__ float sigp(float eq, float ek) {
  return __builtin_amdgcn_rcpf(fmaf(eq, ek, 1.0f));
}

// ---------------------------------------------------------------------------
// K1: both projections in one launch; emits Eq/Ek = exp2(kC2 * (X@W)).
// ---------------------------------------------------------------------------
__global__ __launch_bounds__(256) void proj_both(
    const float* __restrict__ queries, const float* __restrict__ keys,
    const float* __restrict__ Wq, const float* __restrict__ Wk,
    float* __restrict__ eq, float* __restrict__ ek) {
  const int bid = blockIdx.x;
  const bool isK = bid >= 128;
  const float* X = isK ? keys : queries;
  const float* W = isK ? Wk : Wq;
  float* Y = isK ? ek : eq;
  const long long base = (long long)(bid & 127) * 64 * 64;

  __shared__ __align__(16) float xs[64][68];
  __shared__ __align__(16) float ws[64][64];
  const int t = threadIdx.x;
  {
    const int r = t >> 4, sl = t & 15;
#pragma unroll
    for (int i = 0; i < 4; ++i) {
      *(float4*)&xs[r + i * 16][sl * 4] =
          *(const float4*)&X[base + (long long)(r + i * 16) * 64 + sl * 4];
      *(float4*)&ws[r + i * 16][sl * 4] =
          *(const float4*)&W[(r + i * 16) * 64 + sl * 4];
    }
  }
  __syncthreads();

  const int r = t >> 2;
  const int c0 = (t & 3) * 16;
  float acc[16];
#pragma unroll
  for (int j = 0; j < 16; ++j) acc[j] = 0.0f;

#pragma unroll 8
  for (int d = 0; d < 64; ++d) {
    const float xv = xs[r][d];
#pragma unroll
    for (int j4 = 0; j4 < 4; ++j4) {
      float4 w4 = *(float4*)&ws[d][c0 + j4 * 4];
      acc[j4 * 4 + 0] = fmaf(xv, w4.x, acc[j4 * 4 + 0]);
      acc[j4 * 4 + 1] = fmaf(xv, w4.y, acc[j4 * 4 + 1]);
      acc[j4 * 4 + 2] = fmaf(xv, w4.z, acc[j4 * 4 + 2]);
      acc[j4 * 4 + 3] = fmaf(xv, w4.w, acc[j4 * 4 + 3]);
    }
  }
#pragma unroll
  for (int j4 = 0; j4 < 4; ++j4) {
    float4 o = make_float4(__builtin_amdgcn_exp2f(acc[j4 * 4 + 0] * kC2),
                           __builtin_amdgcn_exp2f(acc[j4 * 4 + 1] * kC2),
                           __builtin_amdgcn_exp2f(acc[j4 * 4 + 2] * kC2),
                           __builtin_amdgcn_exp2f(acc[j4 * 4 + 3] * kC2));
    *(float4*)&Y[base + (long long)r * 64 + c0 + j4 * 4] = o;
  }
}

// ---------------------------------------------------------------------------
// K2: scores[b,q,k] = sumw - 2*sum_h wv[h]*rcp(1 + Eq*Ek)
// Worklist item = (b, ktile, qpair): 64 q-rows x 64 k per block, processed as
// two 32q subtiles sharing the ks tile (amortizes k-load + block startup).
// 512 threads, thread owns 1q x 4k; register-double-buffered h pipeline.
// ---------------------------------------------------------------------------
__global__ __launch_bounds__(512, 6) void scores_kernel(
    const float* __restrict__ eqp, const float* __restrict__ ekp,
    const float* __restrict__ wv, const int* __restrict__ vlens,
    float* __restrict__ scores) {
  // uniform worklist mapping (scalar)
  int pre[9];
  pre[0] = 0;
#pragma unroll
  for (int bb = 0; bb < 8; ++bb) {
    int nt = (vlens[bb] + 63) >> 6;
    nt = nt < 16 ? nt : 16;
    pre[bb + 1] = pre[bb] + (nt << 4);  // nt k-tiles x 16 q-pairs
  }
  const int g = blockIdx.x;
  if (g >= pre[8]) return;
  int b = 0;
#pragma unroll
  for (int i = 0; i < 7; ++i) b += (g >= pre[i + 1]);
  const int local = g - pre[b];
  const int q0 = (local & 15) * 64;  // q-pair fastest
  const int k0 = (local >> 4) * 64;

  __shared__ __align__(16) float qsA[32][68];
  __shared__ __align__(16) float qsB[32][68];
  __shared__ __align__(16) float ks[64][64];
  const int t = threadIdx.x;

  float sumw = 0.0f;
#pragma unroll
  for (int h = 0; h < 64; ++h) sumw += wv[h];  // uniform -> scalar loads

  {
    const int r = t >> 4, sl = t & 15;
    *(float4*)&qsA[r][sl * 4] =
        *(const float4*)&eqp[(long long)(b * QDIM + q0 + r) * 64 + sl * 4];
    *(float4*)&qsB[r][sl * 4] =
        *(const float4*)&eqp[(long long)(b * QDIM + q0 + 32 + r) * 64 + sl * 4];
  }
#pragma unroll
  for (int i = 0; i < 2; ++i) {
    const int f = i * 512 + t;
    const int k = f >> 4, sl = f & 15;
    const int key = (k ^ (k >> 2)) & 15;
    *(float4*)&ks[k][(sl ^ key) * 4] =
        *(const float4*)&ekp[(long long)(b * KDIM + k0 + k) * 64 + sl * 4];
  }
  __syncthreads();

  const int tq = t >> 4;            // 0..31: q row within subtile
  const int kg = t & 15;            // k group
  const int kbs = kg << 2;
  const int key0 = ((kbs + 0) ^ kg) & 15;
  const int key1 = ((kbs + 1) ^ kg) & 15;
  const int key2 = ((kbs + 2) ^ kg) & 15;
  const int key3 = ((kbs + 3) ^ kg) & 15;

  float4 qA, kA0, kA1, kA2, kA3;
  float4 qB, kB0, kB1, kB2, kB3;

#define LOAD_STAGE(QS, QF, K0, K1, K2, K3, H)              \
  QF = *(const float4*)&QS[tq][(H) * 4];                   \
  K0 = *(const float4*)&ks[kbs + 0][((H) ^ key0) * 4];     \
  K1 = *(const float4*)&ks[kbs + 1][((H) ^ key1) * 4];     \
  K2 = *(const float4*)&ks[kbs + 2][((H) ^ key2) * 4];     \
  K3 = *(const float4*)&ks[kbs + 3][((H) ^ key3) * 4];

#define COMP_STAGE(QF, K0, K1, K2, K3, H)                  \
  {                                                        \
    const float w0 = wv[(H) * 4 + 0];                      \
    const float w1 = wv[(H) * 4 + 1];                      \
    const float w2 = wv[(H) * 4 + 2];                      \
    const float w3 = wv[(H) * 4 + 3];                      \
    acc0 = fmaf(w0, sigp(QF.x, K0.x), acc0);               \
    acc1 = fmaf(w0, sigp(QF.x, K1.x), acc1);               \
    acc2 = fmaf(w0, sigp(QF.x, K2.x), acc2);               \
    acc3 = fmaf(w0, sigp(QF.x, K3.x), acc3);               \
    acc0 = fmaf(w1, sigp(QF.y, K0.y), acc0);               \
    acc1 = fmaf(w1, sigp(QF.y, K1.y), acc1);               \
    acc2 = fmaf(w1, sigp(QF.y, K2.y), acc2);               \
    acc3 = fmaf(w1, sigp(QF.y, K3.y), acc3);               \
    acc0 = fmaf(w2, sigp(QF.z, K0.z), acc0);               \
    acc1 = fmaf(w2, sigp(QF.z, K1.z), acc1);               \
    acc2 = fmaf(w2, sigp(QF.z, K2.z), acc2);               \
    acc3 = fmaf(w2, sigp(QF.z, K3.z), acc3);               \
    acc0 = fmaf(w3, sigp(QF.w, K0.w), acc0);               \
    acc1 = fmaf(w3, sigp(QF.w, K1.w), acc1);               \
    acc2 = fmaf(w3, sigp(QF.w, K2.w), acc2);               \
    acc3 = fmaf(w3, sigp(QF.w, K3.w), acc3);               \
  }

#define SUBTILE(QS, QOFF)                                                    \
  {                                                                          \
    float acc0 = 0.0f, acc1 = 0.0f, acc2 = 0.0f, acc3 = 0.0f;                \
    LOAD_STAGE(QS, qA, kA0, kA1, kA2, kA3, 0)                                \
    _Pragma("unroll")                                                        \
    for (int h = 0; h < 16; h += 2) {                                        \
      LOAD_STAGE(QS, qB, kB0, kB1, kB2, kB3, h + 1)                          \
      COMP_STAGE(qA, kA0, kA1, kA2, kA3, h)                                  \
      if (h + 2 < 16) LOAD_STAGE(QS, qA, kA0, kA1, kA2, kA3, h + 2)          \
      COMP_STAGE(qB, kB0, kB1, kB2, kB3, h + 1)                              \
    }                                                                        \
    float4 o = make_float4(fmaf(-2.0f, acc0, sumw), fmaf(-2.0f, acc1, sumw), \
                           fmaf(-2.0f, acc2, sumw), fmaf(-2.0f, acc3, sumw));\
    *(float4*)&scores[(long long)(b * QDIM + q0 + (QOFF) + tq) * KDIM +      \
                      k0 + kbs] = o;                                         \
  }

  SUBTILE(qsA, 0)
  SUBTILE(qsB, 32)

#undef SUBTILE
#undef LOAD_STAGE
#undef COMP_STAGE
}

// ---------------------------------------------------------------------------
// K3: fused masked-softmax + PV (flash-style over materialized scores).
// Block = 256 threads = 16 q-rows x 16 lanes. Per k-tile: load V->LDS, read
// S tile, online (m,l) update, p->LDS, PV accumulate into registers.
// Never writes scores back; out written once at the end.
// ---------------------------------------------------------------------------
__global__ __launch_bounds__(256) void softpv_kernel(
    const float* __restrict__ scores, const float* __restrict__ V,
    const int* __restrict__ vlens, float* __restrict__ out) {
  const int b = blockIdx.y;
  const int q0 = blockIdx.x * 16;
  const int vlen = vlens[b];
  const int ntiles = (vlen + 63) >> 6;

  __shared__ __align__(16) float vs[64][64];
  __shared__ __align__(16) float ps[16][68];
  const int t = threadIdx.x;
  const int r = t >> 4;           // q row 0..15
  const int kg = t & 15;
  const int dsl = kg * 4;
  const float* srow = scores + (long long)(b * QDIM + q0 + r) * KDIM;

  float4 o = make_float4(0, 0, 0, 0);
  float m = -3.0e38f, l = 0.0f;

  for (int kt = 0; kt < ntiles; ++kt) {
    // V tile -> LDS
#pragma unroll
    for (int i = 0; i < 4; ++i) {
      const int f = i * 256 + t;
      const int k = f >> 4, sl = f & 15;
      *(float4*)&vs[k][sl * 4] =
          *(const float4*)&V[(long long)(b * KDIM + kt * 64 + k) * 64 + sl * 4];
    }
    // S tile (this thread's 4 k) + mask
    const int kbase = kt * 64 + kg * 4;
    float4 s4 = *(const float4*)&srow[kbase];
    s4.x = (kbase + 0 < vlen) ? s4.x : -3.0e38f;
    s4.y = (kbase + 1 < vlen) ? s4.y : -3.0e38f;
    s4.z = (kbase + 2 < vlen) ? s4.z : -3.0e38f;
    s4.w = (kbase + 3 < vlen) ? s4.w : -3.0e38f;
    float tm = fmaxf(fmaxf(s4.x, s4.y), fmaxf(s4.z, s4.w));
#pragma unroll
    for (int s = 1; s < 16; s <<= 1) tm = fmaxf(tm, __shfl_xor(tm, s, 64));
    const float mn = fmaxf(m, tm);
    const float scale = __builtin_amdgcn_exp2f((m - mn) * kLog2e);
    float4 p;
    p.x = __builtin_amdgcn_exp2f((s4.x - mn) * kLog2e);
    p.y = __builtin_amdgcn_exp2f((s4.y - mn) * kLog2e);
    p.z = __builtin_amdgcn_exp2f((s4.z - mn) * kLog2e);
    p.w = __builtin_amdgcn_exp2f((s4.w - mn) * kLog2e);
    l = fmaf(l, scale, (p.x + p.y) + (p.z + p.w));
    o.x *= scale; o.y *= scale; o.z *= scale; o.w *= scale;
    m = mn;
    *(float4*)&ps[r][kg * 4] = p;
    __syncthreads();

    // PV: o[dsl..dsl+3] += sum_k p[r][k] * V[k][dsl..]
#pragma unroll 4
    for (int k4 = 0; k4 < 16; ++k4) {
      const float4 p4 = *(const float4*)&ps[r][k4 * 4];
      const float pw[4] = {p4.x, p4.y, p4.z, p4.w};
#pragma unroll
      for (int e = 0; e < 4; ++e) {
        const float4 vv = *(const float4*)&vs[k4 * 4 + e][dsl];
        o.x = fmaf(pw[e], vv.x, o.x);
        o.y = fmaf(pw[e], vv.y, o.y);
        o.z = fmaf(pw[e], vv.z, o.z);
        o.w = fmaf(pw[e], vv.w, o.w);
      }
    }
    __syncthreads();
  }

#pragma unroll
  for (int s = 1; s < 16; s <<= 1) l += __shfl_xor(l, s, 64);
  const float inv = __builtin_amdgcn_rcpf(l);
  float4 res = make_float4(o.x * inv, o.y * inv, o.z * inv, o.w * inv);
  *(float4*)&out[(long long)(b * QDIM + q0 + r) * 64 + dsl] = res;
}

// ---------------------------------------------------------------------------
extern "C" void kernel_launch(void* const* d_in, const int* in_sizes, int n_in,
                              void* d_out, int out_size, void* d_ws, size_t ws_size,
                              hipStream_t stream) {
  const float* queries = (const float*)d_in[0];
  const float* keys    = (const float*)d_in[1];
  const float* values  = (const float*)d_in[2];
  const int*   vlens   = (const int*)d_in[3];
  const float* Wq      = (const float*)d_in[4];
  const float* Wk      = (const float*)d_in[5];
  const float* wv      = (const float*)d_in[6];
  float* out = (float*)d_out;

  float* eq     = (float*)d_ws;                       // B*Q*H  = 2 MB (exp2'd)
  float* ek     = eq + (size_t)BDIM * QDIM * HDIM;    // B*K*H  = 2 MB (exp2'd)
  float* scores = ek + (size_t)BDIM * KDIM * HDIM;    // B*Q*K  = 32 MB

  proj_both<<<dim3(256), 256, 0, stream>>>(queries, keys, Wq, Wk, eq, ek);
  // max items = 8 b * 16 q-pairs * 16 k-tiles = 2048; invalid tail exits fast.
  scores_kernel<<<dim3(2048), 512, 0, stream>>>(eq, ek, wv, vlens, scores);
  softpv_kernel<<<dim3(QDIM / 16, BDIM), 256, 0, stream>>>(scores, values,
                                                           vlens, out);
}

// Round 5
// 76.982 us; speedup vs baseline: 6.1233x; 6.1233x over previous
//
#include <hip/hip_runtime.h>

// Problem sizes (fixed by the reference)
#define BDIM 8
#define QDIM 1024
#define KDIM 1024
#define HDIM 64   // = DQ = DK = DV

constexpr float kLog2e = 1.4426950408889634f;
constexpr float kC2 = 2.0f * kLog2e;

// tanh(x) = 1 - 2/(1 + e^{2x}); e^{2x} = Eq*Ek with Eq=2^{kC2*qhat},
// Ek=2^{kC2*khat} precomputed. Per element: 3 VALU ops (fma, rcp, fma).
// Rails exact: Eq*Ek -> inf => rcp -> 0 => tanh -> 1.
__device__ __forceinline__ float sigp(float eq, float ek) {
  return __builtin_amdgcn_rcpf(fmaf(eq, ek, 1.0f));
}

// ---------------------------------------------------------------------------
// K1: both projections in one launch; emits Eq/Ek = exp2(kC2 * (X@W)).
// ---------------------------------------------------------------------------
__global__ __launch_bounds__(256) void proj_both(
    const float* __restrict__ queries, const float* __restrict__ keys,
    const float* __restrict__ Wq, const float* __restrict__ Wk,
    float* __restrict__ eq, float* __restrict__ ek) {
  const int bid = blockIdx.x;
  const bool isK = bid >= 128;
  const float* X = isK ? keys : queries;
  const float* W = isK ? Wk : Wq;
  float* Y = isK ? ek : eq;
  const long long base = (long long)(bid & 127) * 64 * 64;

  __shared__ __align__(16) float xs[64][68];
  __shared__ __align__(16) float ws[64][64];
  const int t = threadIdx.x;
  {
    const int r = t >> 4, sl = t & 15;
#pragma unroll
    for (int i = 0; i < 4; ++i) {
      *(float4*)&xs[r + i * 16][sl * 4] =
          *(const float4*)&X[base + (long long)(r + i * 16) * 64 + sl * 4];
      *(float4*)&ws[r + i * 16][sl * 4] =
          *(const float4*)&W[(r + i * 16) * 64 + sl * 4];
    }
  }
  __syncthreads();

  const int r = t >> 2;
  const int c0 = (t & 3) * 16;
  float acc[16];
#pragma unroll
  for (int j = 0; j < 16; ++j) acc[j] = 0.0f;

#pragma unroll 8
  for (int d = 0; d < 64; ++d) {
    const float xv = xs[r][d];
#pragma unroll
    for (int j4 = 0; j4 < 4; ++j4) {
      float4 w4 = *(float4*)&ws[d][c0 + j4 * 4];
      acc[j4 * 4 + 0] = fmaf(xv, w4.x, acc[j4 * 4 + 0]);
      acc[j4 * 4 + 1] = fmaf(xv, w4.y, acc[j4 * 4 + 1]);
      acc[j4 * 4 + 2] = fmaf(xv, w4.z, acc[j4 * 4 + 2]);
      acc[j4 * 4 + 3] = fmaf(xv, w4.w, acc[j4 * 4 + 3]);
    }
  }
#pragma unroll
  for (int j4 = 0; j4 < 4; ++j4) {
    float4 o = make_float4(__builtin_amdgcn_exp2f(acc[j4 * 4 + 0] * kC2),
                           __builtin_amdgcn_exp2f(acc[j4 * 4 + 1] * kC2),
                           __builtin_amdgcn_exp2f(acc[j4 * 4 + 2] * kC2),
                           __builtin_amdgcn_exp2f(acc[j4 * 4 + 3] * kC2));
    *(float4*)&Y[base + (long long)r * 64 + c0 + j4 * 4] = o;
  }
}

// ---------------------------------------------------------------------------
// K2: scores[b,q,k] = sumw - 2*sum_h wv[h]*rcp(1 + Eq*Ek)
// EXACT round-3 structure (known-good: VGPR=40, no spills, VALUBusy 73%):
// compacted worklist, tile 32q x 64k, 512 threads, 1q x 4k per thread,
// register double-buffered h-pipeline. Only the per-element math changed.
// ---------------------------------------------------------------------------
__global__ __launch_bounds__(512, 6) void scores_kernel(
    const float* __restrict__ eqp, const float* __restrict__ ekp,
    const float* __restrict__ wv, const int* __restrict__ vlens,
    float* __restrict__ scores) {
  // ---- uniform worklist mapping (scalar) ----
  int pre[9];
  pre[0] = 0;
#pragma unroll
  for (int bb = 0; bb < 8; ++bb) {
    int nt = (vlens[bb] + 63) >> 6;
    nt = nt < 16 ? nt : 16;
    pre[bb + 1] = pre[bb] + (nt << 5);  // nt k-tiles x 32 q-tiles
  }
  const int g = blockIdx.x;
  if (g >= pre[8]) return;
  int b = 0;
#pragma unroll
  for (int i = 0; i < 7; ++i) b += (g >= pre[i + 1]);
  const int local = g - pre[b];
  const int q0 = (local & 31) * 32;  // q-tile fastest
  const int k0 = (local >> 5) * 64;

  __shared__ __align__(16) float qs[32][68];
  __shared__ __align__(16) float ks[64][64];
  const int t = threadIdx.x;

  float sumw = 0.0f;
#pragma unroll
  for (int h = 0; h < 64; ++h) sumw += wv[h];  // uniform -> scalar loads

  {
    const int r = t >> 4, sl = t & 15;
    *(float4*)&qs[r][sl * 4] =
        *(const float4*)&eqp[(long long)(b * QDIM + q0 + r) * 64 + sl * 4];
  }
#pragma unroll
  for (int i = 0; i < 2; ++i) {
    const int f = i * 512 + t;
    const int k = f >> 4, sl = f & 15;
    const int key = (k ^ (k >> 2)) & 15;
    *(float4*)&ks[k][(sl ^ key) * 4] =
        *(const float4*)&ekp[(long long)(b * KDIM + k0 + k) * 64 + sl * 4];
  }
  __syncthreads();

  const int tq = t >> 4;            // 0..31: q row
  const int kg = t & 15;            // k group
  const int kbs = kg << 2;          // k base = 4*kg
  const int key0 = ((kbs + 0) ^ kg) & 15;
  const int key1 = ((kbs + 1) ^ kg) & 15;
  const int key2 = ((kbs + 2) ^ kg) & 15;
  const int key3 = ((kbs + 3) ^ kg) & 15;

  float acc0 = 0.0f, acc1 = 0.0f, acc2 = 0.0f, acc3 = 0.0f;

  float4 qA, kA0, kA1, kA2, kA3;
  float4 qB, kB0, kB1, kB2, kB3;

#define LOAD_STAGE(QF, K0, K1, K2, K3, H)                  \
  QF = *(const float4*)&qs[tq][(H) * 4];                   \
  K0 = *(const float4*)&ks[kbs + 0][((H) ^ key0) * 4];     \
  K1 = *(const float4*)&ks[kbs + 1][((H) ^ key1) * 4];     \
  K2 = *(const float4*)&ks[kbs + 2][((H) ^ key2) * 4];     \
  K3 = *(const float4*)&ks[kbs + 3][((H) ^ key3) * 4];

#define COMP_STAGE(QF, K0, K1, K2, K3, H)                  \
  {                                                        \
    const float w0 = wv[(H) * 4 + 0];                      \
    const float w1 = wv[(H) * 4 + 1];                      \
    const float w2 = wv[(H) * 4 + 2];                      \
    const float w3 = wv[(H) * 4 + 3];                      \
    acc0 = fmaf(w0, sigp(QF.x, K0.x), acc0);               \
    acc1 = fmaf(w0, sigp(QF.x, K1.x), acc1);               \
    acc2 = fmaf(w0, sigp(QF.x, K2.x), acc2);               \
    acc3 = fmaf(w0, sigp(QF.x, K3.x), acc3);               \
    acc0 = fmaf(w1, sigp(QF.y, K0.y), acc0);               \
    acc1 = fmaf(w1, sigp(QF.y, K1.y), acc1);               \
    acc2 = fmaf(w1, sigp(QF.y, K2.y), acc2);               \
    acc3 = fmaf(w1, sigp(QF.y, K3.y), acc3);               \
    acc0 = fmaf(w2, sigp(QF.z, K0.z), acc0);               \
    acc1 = fmaf(w2, sigp(QF.z, K1.z), acc1);               \
    acc2 = fmaf(w2, sigp(QF.z, K2.z), acc2);               \
    acc3 = fmaf(w2, sigp(QF.z, K3.z), acc3);               \
    acc0 = fmaf(w3, sigp(QF.w, K0.w), acc0);               \
    acc1 = fmaf(w3, sigp(QF.w, K1.w), acc1);               \
    acc2 = fmaf(w3, sigp(QF.w, K2.w), acc2);               \
    acc3 = fmaf(w3, sigp(QF.w, K3.w), acc3);               \
  }

  LOAD_STAGE(qA, kA0, kA1, kA2, kA3, 0)
#pragma unroll
  for (int h = 0; h < 16; h += 2) {
    LOAD_STAGE(qB, kB0, kB1, kB2, kB3, h + 1)
    COMP_STAGE(qA, kA0, kA1, kA2, kA3, h)
    if (h + 2 < 16) LOAD_STAGE(qA, kA0, kA1, kA2, kA3, h + 2)
    COMP_STAGE(qB, kB0, kB1, kB2, kB3, h + 1)
  }
#undef LOAD_STAGE
#undef COMP_STAGE

  float4 o = make_float4(fmaf(-2.0f, acc0, sumw), fmaf(-2.0f, acc1, sumw),
                         fmaf(-2.0f, acc2, sumw), fmaf(-2.0f, acc3, sumw));
  *(float4*)&scores[(long long)(b * QDIM + q0 + tq) * KDIM + k0 + kbs] = o;
}

// ---------------------------------------------------------------------------
// K3: fused masked-softmax + PV (flash-style over materialized scores).
// Block = 256 threads = 16 q-rows x 16 lanes. Per k-tile: load V->LDS, read
// S tile, online (m,l) update, p->LDS, PV accumulate into registers.
// ---------------------------------------------------------------------------
__global__ __launch_bounds__(256) void softpv_kernel(
    const float* __restrict__ scores, const float* __restrict__ V,
    const int* __restrict__ vlens, float* __restrict__ out) {
  const int b = blockIdx.y;
  const int q0 = blockIdx.x * 16;
  const int vlen = vlens[b];
  const int ntiles = (vlen + 63) >> 6;

  __shared__ __align__(16) float vs[64][64];
  __shared__ __align__(16) float ps[16][68];
  const int t = threadIdx.x;
  const int r = t >> 4;           // q row 0..15
  const int kg = t & 15;
  const int dsl = kg * 4;
  const float* srow = scores + (long long)(b * QDIM + q0 + r) * KDIM;

  float4 o = make_float4(0, 0, 0, 0);
  float m = -3.0e38f, l = 0.0f;

  for (int kt = 0; kt < ntiles; ++kt) {
    // V tile -> LDS
#pragma unroll
    for (int i = 0; i < 4; ++i) {
      const int f = i * 256 + t;
      const int k = f >> 4, sl = f & 15;
      *(float4*)&vs[k][sl * 4] =
          *(const float4*)&V[(long long)(b * KDIM + kt * 64 + k) * 64 + sl * 4];
    }
    // S tile (this thread's 4 k) + mask
    const int kbase = kt * 64 + kg * 4;
    float4 s4 = *(const float4*)&srow[kbase];
    s4.x = (kbase + 0 < vlen) ? s4.x : -3.0e38f;
    s4.y = (kbase + 1 < vlen) ? s4.y : -3.0e38f;
    s4.z = (kbase + 2 < vlen) ? s4.z : -3.0e38f;
    s4.w = (kbase + 3 < vlen) ? s4.w : -3.0e38f;
    float tm = fmaxf(fmaxf(s4.x, s4.y), fmaxf(s4.z, s4.w));
#pragma unroll
    for (int s = 1; s < 16; s <<= 1) tm = fmaxf(tm, __shfl_xor(tm, s, 64));
    const float mn = fmaxf(m, tm);
    const float scale = __builtin_amdgcn_exp2f((m - mn) * kLog2e);
    float4 p;
    p.x = __builtin_amdgcn_exp2f((s4.x - mn) * kLog2e);
    p.y = __builtin_amdgcn_exp2f((s4.y - mn) * kLog2e);
    p.z = __builtin_amdgcn_exp2f((s4.z - mn) * kLog2e);
    p.w = __builtin_amdgcn_exp2f((s4.w - mn) * kLog2e);
    l = fmaf(l, scale, (p.x + p.y) + (p.z + p.w));
    o.x *= scale; o.y *= scale; o.z *= scale; o.w *= scale;
    m = mn;
    *(float4*)&ps[r][kg * 4] = p;
    __syncthreads();

    // PV: o[dsl..dsl+3] += sum_k p[r][k] * V[k][dsl..]
#pragma unroll 4
    for (int k4 = 0; k4 < 16; ++k4) {
      const float4 p4 = *(const float4*)&ps[r][k4 * 4];
      const float pw[4] = {p4.x, p4.y, p4.z, p4.w};
#pragma unroll
      for (int e = 0; e < 4; ++e) {
        const float4 vv = *(const float4*)&vs[k4 * 4 + e][dsl];
        o.x = fmaf(pw[e], vv.x, o.x);
        o.y = fmaf(pw[e], vv.y, o.y);
        o.z = fmaf(pw[e], vv.z, o.z);
        o.w = fmaf(pw[e], vv.w, o.w);
      }
    }
    __syncthreads();
  }

#pragma unroll
  for (int s = 1; s < 16; s <<= 1) l += __shfl_xor(l, s, 64);
  const float inv = __builtin_amdgcn_rcpf(l);
  float4 res = make_float4(o.x * inv, o.y * inv, o.z * inv, o.w * inv);
  *(float4*)&out[(long long)(b * QDIM + q0 + r) * 64 + dsl] = res;
}

// ---------------------------------------------------------------------------
extern "C" void kernel_launch(void* const* d_in, const int* in_sizes, int n_in,
                              void* d_out, int out_size, void* d_ws, size_t ws_size,
                              hipStream_t stream) {
  const float* queries = (const float*)d_in[0];
  const float* keys    = (const float*)d_in[1];
  const float* values  = (const float*)d_in[2];
  const int*   vlens   = (const int*)d_in[3];
  const float* Wq      = (const float*)d_in[4];
  const float* Wk      = (const float*)d_in[5];
  const float* wv      = (const float*)d_in[6];
  float* out = (float*)d_out;

  float* eq     = (float*)d_ws;                       // B*Q*H  = 2 MB (exp2'd)
  float* ek     = eq + (size_t)BDIM * QDIM * HDIM;    // B*K*H  = 2 MB (exp2'd)
  float* scores = ek + (size_t)BDIM * KDIM * HDIM;    // B*Q*K  = 32 MB

  proj_both<<<dim3(256), 256, 0, stream>>>(queries, keys, Wq, Wk, eq, ek);
  // max tiles = 8 b * 32 q-tiles * 16 k-tiles = 4096; invalid tail exits fast.
  scores_kernel<<<dim3(4096), 512, 0, stream>>>(eq, ek, wv, vlens, scores);
  softpv_kernel<<<dim3(QDIM / 16, BDIM), 256, 0, stream>>>(scores, values,
                                                           vlens, out);
}